// Round 2
// baseline (6726.920 us; speedup 1.0000x reference)
//
#include <hip/hip_runtime.h>
#include <stdint.h>

typedef unsigned int   u32;
typedef unsigned short u16;
typedef __attribute__((ext_vector_type(8))) short bf16x8;
typedef __attribute__((ext_vector_type(4))) float f32x4;

#define T_DIM  512
#define B_DIM  256
#define D_DIM  256
#define H_DIM  256
#define O_DIM  64
#define BB     16     // batches per group
#define NJ     8      // workgroups per group
#define JU     32     // hidden units per wg
#define JC     128    // gate columns per wg (4 gates * JU)
#define NGRP   16
#define NWG    128
#define NTHR   256
#define KT_CNT 16     // K=512 / 32
#define NT_CNT 8      // 128 cols / 16
#define APITCH_B 1040 // bytes per A row (520 bf16, padded vs 512 to dodge bank conflicts)
#define GPITCH 132    // f32 per gates row (padded)

#define WFRAG_OFF 0
#define A_OFF     131072
#define GATES_OFF 147712
#define BIAS_OFF  156160
#define LENS_OFF  156672
#define MAXL_OFF  156736
#define SMEM_SZ   156752

__device__ __forceinline__ u16 f2bf(float f) {
  u32 u = __float_as_uint(f);
  u32 r = u + 0x7fffu + ((u >> 16) & 1u);   // RNE bf16
  return (u16)(r >> 16);
}
__device__ __forceinline__ float sigmoidf_(float x) {
  return 1.0f / (1.0f + __expf(-x));        // exp(+inf)->inf -> 0, no NaN
}
__device__ __forceinline__ float tanhf_(float x) {
  x = fminf(fmaxf(x, -40.0f), 40.0f);       // keep expf finite
  float e = __expf(-2.0f * x);
  return (1.0f - e) / (1.0f + e);
}

__global__ __launch_bounds__(NTHR, 1)
void lstm_coop(const float* __restrict__ x, const int* __restrict__ lengths,
               const float* __restrict__ Wf, const float* __restrict__ bfp,
               const float* __restrict__ Wi, const float* __restrict__ bip,
               const float* __restrict__ Wc, const float* __restrict__ bcp,
               const float* __restrict__ Wo, const float* __restrict__ bop,
               const float* __restrict__ Wy, const float* __restrict__ byp,
               float* out, u16* hbuf, u32* cnt)
{
  extern __shared__ char smem[];
  char*  Wfrag = smem + WFRAG_OFF;          // 128KB: W slice, B-fragment order, bf16
  char*  Abuf  = smem + A_OFF;              // 16 x 520 bf16 : [x_t | h]
  float* gates = (float*)(smem + GATES_OFF);// 16 x 132 f32
  float* biasS = (float*)(smem + BIAS_OFF); // 128 f32
  int*   lensS = (int*)(smem + LENS_OFF);   // 16
  int*   maxlS = (int*)(smem + MAXL_OFF);

  const int tid = threadIdx.x;
  // group members are blockIdx {g, g+16, ..., g+112} -> same value mod 8
  // (likely same XCD under round-robin dispatch; correctness doesn't rely on it)
  const int g   = blockIdx.x & (NGRP - 1);
  const int ji  = blockIdx.x >> 4;
  const int b0  = g * BB;
  const int u0  = ji * JU;

  // ---------- one-time: weight slice -> LDS in MFMA B-fragment order ----------
  {
    const float* Wg_[4] = {Wf, Wi, Wc, Wo};
    for (int idx = tid; idx < NT_CNT * KT_CNT * 64; idx += NTHR) {
      int n  = idx >> 10;           // n-tile (16 cols)
      int kt = (idx >> 6) & 15;     // k-tile (32 k)
      int l  = idx & 63;            // lane
      int cl = n * 16 + (l & 15);   // local gate-col 0..127: [f|i|c|o] x 32 units
      const float* W = Wg_[cl >> 5];
      int col = u0 + (cl & 31);
      int k0  = kt * 32 + (l >> 4) * 8;
      uint4 v;
      u32* pv = (u32*)&v;
      #pragma unroll
      for (int m = 0; m < 4; m++) {
        float f0 = W[(size_t)(k0 + 2*m    ) * H_DIM + col];
        float f1 = W[(size_t)(k0 + 2*m + 1) * H_DIM + col];
        pv[m] = (u32)f2bf(f0) | ((u32)f2bf(f1) << 16);
      }
      *(uint4*)(Wfrag + (size_t)idx * 16) = v;
    }
    const float* bg_[4] = {bfp, bip, bcp, bop};
    if (tid < JC) biasS[tid] = bg_[tid >> 5][u0 + (tid & 31)];
    if (tid < BB) lensS[tid] = lengths[b0 + tid];
  }
  __syncthreads();
  if (tid == 0) {
    int m = 1;
    for (int r = 0; r < BB; r++) m = max(m, lensS[r]);
    maxlS[0] = m;
  }
  __syncthreads();
  const int Tmax = maxlS[0];

  // per-thread persistent state: 2 adjacent (b,u) cells
  const int pb = tid >> 4;          // batch row in block
  const int pu = (tid * 2) & 31;    // even unit within slice
  const int lenb = lensS[pb];
  float cst0 = 0.f, cst1 = 0.f, hst0 = 0.f, hst1 = 0.f;

  const int l    = tid & 63;
  const int wv   = tid >> 6;        // wave 0..3, owns n-tiles {2wv, 2wv+1}
  const int arow = l & 15;
  const int kh   = l >> 4;
  const char* Aread  = Abuf + arow * APITCH_B + kh * 16;
  const char* Bbase0 = Wfrag + ((size_t)((2*wv    ) * KT_CNT) * 64 + l) * 16;
  const char* Bbase1 = Wfrag + ((size_t)((2*wv + 1) * KT_CNT) * 64 + l) * 16;
  u32* cslot = cnt + g * 32;        // 128B-spaced per-group barrier counter

  for (int t = 0; t < Tmax; t++) {
    // ---- stage A = [x_t | h_t] as bf16 into LDS ----
    const float* xrow = x + ((size_t)t * B_DIM + b0) * D_DIM;
    #pragma unroll
    for (int i = tid; i < BB * 128; i += NTHR) {
      int r = i >> 7, dp = i & 127;
      float2 xv = *(const float2*)(xrow + (size_t)r * D_DIM + dp * 2);
      *(u32*)(Abuf + r * APITCH_B + dp * 4) =
          (u32)f2bf(xv.x) | ((u32)f2bf(xv.y) << 16);
    }
    const u16* hin = hbuf + (size_t)(t & 1) * (B_DIM * H_DIM);
    #pragma unroll
    for (int i = tid; i < BB * 128; i += NTHR) {
      int r = i >> 7, up = i & 127;
      u32 v = __hip_atomic_load((u32*)(hin + (size_t)(b0 + r) * H_DIM + up * 2),
                                __ATOMIC_RELAXED, __HIP_MEMORY_SCOPE_AGENT);
      *(u32*)(Abuf + r * APITCH_B + 512 + up * 4) = v;
    }
    __syncthreads();

    // ---- GEMM: [16 x 512] @ [512 x 128], f32 accum ----
    f32x4 acc0 = {0.f, 0.f, 0.f, 0.f};
    f32x4 acc1 = {0.f, 0.f, 0.f, 0.f};
    #pragma unroll
    for (int kt = 0; kt < KT_CNT; kt++) {
      bf16x8 a   = *(const bf16x8*)(Aread  + kt * 64);
      bf16x8 b0v = *(const bf16x8*)(Bbase0 + (size_t)kt * 1024);
      bf16x8 b1v = *(const bf16x8*)(Bbase1 + (size_t)kt * 1024);
      acc0 = __builtin_amdgcn_mfma_f32_16x16x32_bf16(a, b0v, acc0, 0, 0, 0);
      acc1 = __builtin_amdgcn_mfma_f32_16x16x32_bf16(a, b1v, acc1, 0, 0, 0);
    }
    #pragma unroll
    for (int r = 0; r < 4; r++) {     // C layout: col=lane&15, row=(lane>>4)*4+r
      int gr = kh * 4 + r;
      gates[gr * GPITCH + (2*wv    ) * 16 + arow] = acc0[r];
      gates[gr * GPITCH + (2*wv + 1) * 16 + arow] = acc1[r];
    }
    __syncthreads();

    // ---- gates + masked state update ----
    {
      const float* gp = gates + pb * GPITCH;
      const bool act = (t < lenb);
      int u = pu;
      float fg = sigmoidf_(gp[u]      + biasS[u]);
      float ig = sigmoidf_(gp[32 + u] + biasS[32 + u]);
      float cg = tanhf_  (gp[64 + u]  + biasS[64 + u]);
      float og = sigmoidf_(gp[96 + u] + biasS[96 + u]);
      if (act) { cst0 = fg * cst0 + ig * cg; hst0 = og * tanhf_(cst0); }
      u = pu + 1;
      fg = sigmoidf_(gp[u]      + biasS[u]);
      ig = sigmoidf_(gp[32 + u] + biasS[32 + u]);
      cg = tanhf_  (gp[64 + u]  + biasS[64 + u]);
      og = sigmoidf_(gp[96 + u] + biasS[96 + u]);
      if (act) { cst1 = fg * cst1 + ig * cg; hst1 = og * tanhf_(cst1); }

      u16* hout = hbuf + (size_t)((t + 1) & 1) * (B_DIM * H_DIM);
      u32 pk = (u32)f2bf(hst0) | ((u32)f2bf(hst1) << 16);
      __hip_atomic_store((u32*)(hout + (size_t)(b0 + pb) * H_DIM + u0 + pu), pk,
                         __ATOMIC_RELAXED, __HIP_MEMORY_SCOPE_AGENT);
    }

    // ---- group barrier (monotonic counter, 8 arrivals per step) ----
    __threadfence();
    __syncthreads();
    if (tid == 0) {
      __hip_atomic_fetch_add(cslot, 1u, __ATOMIC_RELEASE, __HIP_MEMORY_SCOPE_AGENT);
      u32 tgt = (u32)(t + 1) * NJ;
      while (__hip_atomic_load(cslot, __ATOMIC_ACQUIRE, __HIP_MEMORY_SCOPE_AGENT) < tgt)
        __builtin_amdgcn_s_sleep(1);
    }
    __syncthreads();
  }

  // ---- publish final f32 h, extra group barrier, then y = h @ Wy + by ----
  {
    float* hOut = out + (size_t)B_DIM * O_DIM;
    u32* dst = (u32*)(hOut + (size_t)(b0 + pb) * H_DIM + u0 + pu);
    __hip_atomic_store(dst + 0, __float_as_uint(hst0),
                       __ATOMIC_RELAXED, __HIP_MEMORY_SCOPE_AGENT);
    __hip_atomic_store(dst + 1, __float_as_uint(hst1),
                       __ATOMIC_RELAXED, __HIP_MEMORY_SCOPE_AGENT);
  }
  __threadfence();
  __syncthreads();
  if (tid == 0) {
    __hip_atomic_fetch_add(cslot, 1u, __ATOMIC_RELEASE, __HIP_MEMORY_SCOPE_AGENT);
    u32 tgt = (u32)Tmax * NJ + NJ;
    while (__hip_atomic_load(cslot, __ATOMIC_ACQUIRE, __HIP_MEMORY_SCOPE_AGENT) < tgt)
      __builtin_amdgcn_s_sleep(1);
  }
  __syncthreads();

  if (ji == 0) {
    float* hS = (float*)Abuf;                     // reuse A region: 16x256 f32
    const float* hOut = out + (size_t)B_DIM * O_DIM;
    for (int i = tid; i < BB * H_DIM; i += NTHR) {
      int r = i >> 8, u = i & 255;
      u32 v = __hip_atomic_load((u32*)(hOut + (size_t)(b0 + r) * H_DIM + u),
                                __ATOMIC_RELAXED, __HIP_MEMORY_SCOPE_AGENT);
      hS[r * H_DIM + u] = __uint_as_float(v);
    }
    __syncthreads();
    int b = tid >> 4;
    int o = (tid & 15) * 4;
    const float* hrow = hS + b * H_DIM;
    float a0 = 0.f, a1 = 0.f, a2 = 0.f, a3 = 0.f;
    #pragma unroll 4
    for (int u = 0; u < H_DIM; u++) {
      float4 wy = *(const float4*)(Wy + (size_t)u * O_DIM + o);
      float hv = hrow[u];
      a0 = fmaf(hv, wy.x, a0);
      a1 = fmaf(hv, wy.y, a1);
      a2 = fmaf(hv, wy.z, a2);
      a3 = fmaf(hv, wy.w, a3);
    }
    float4 bv = *(const float4*)(byp + o);
    float4 yv = {a0 + bv.x, a1 + bv.y, a2 + bv.z, a3 + bv.w};
    *(float4*)(out + (size_t)(b0 + b) * O_DIM + o) = yv;
  }
}

extern "C" void kernel_launch(void* const* d_in, const int* in_sizes, int n_in,
                              void* d_out, int out_size, void* d_ws, size_t ws_size,
                              hipStream_t stream)
{
  (void)in_sizes; (void)n_in; (void)out_size; (void)ws_size;
  const float* x   = (const float*)d_in[0];
  const int*   ln  = (const int*)d_in[1];
  const float* Wf  = (const float*)d_in[2];
  const float* bf_ = (const float*)d_in[3];
  const float* Wi  = (const float*)d_in[4];
  const float* bi_ = (const float*)d_in[5];
  const float* Wc  = (const float*)d_in[6];
  const float* bc_ = (const float*)d_in[7];
  const float* Wo  = (const float*)d_in[8];
  const float* bo_ = (const float*)d_in[9];
  const float* Wy  = (const float*)d_in[10];
  const float* by_ = (const float*)d_in[11];
  float* out = (float*)d_out;

  // ws layout: [0,2048) barrier counters (128B/group) | [2048, +128K) h buf0 | +128K h buf1
  u32* cnt  = (u32*)d_ws;
  u16* hbuf = (u16*)((char*)d_ws + 2048);
  hipMemsetAsync(d_ws, 0, 2048 + (size_t)B_DIM * H_DIM * 2, stream); // zero counters + h0

  void* args[] = {&x, &ln, &Wf, &bf_, &Wi, &bi_, &Wc, &bc_, &Wo, &bo_,
                  &Wy, &by_, &out, &hbuf, &cnt};
  hipLaunchCooperativeKernel((void*)lstm_coop, dim3(NWG), dim3(NTHR),
                             args, SMEM_SZ, stream);
}

// Round 3
// 3754.159 us; speedup vs baseline: 1.7919x; 1.7919x over previous
//
#include <hip/hip_runtime.h>
#include <stdint.h>

typedef unsigned int   u32;
typedef unsigned short u16;
typedef __attribute__((ext_vector_type(8))) short bf16x8;
typedef __attribute__((ext_vector_type(4))) float f32x4;

#define B_DIM  256
#define D_DIM  256
#define H_DIM  256
#define O_DIM  64
#define BB     16     // batches per group
#define NJ     8      // workgroups per group
#define JU     32     // hidden units per wg
#define JC     128    // gate columns per wg (4 gates * JU)
#define NGRP   16
#define NWG    128
#define NTHR   256
#define KT_CNT 16     // K=512 / 32
#define KT_X   8      // k-tiles covering x (K 0..255)
#define NT_CNT 8      // 128 cols / 16
#define APITCH_B 528  // bytes per A row (264 bf16; x only now). (4r+c)%32 -> 2-way, free
#define GPITCH 132    // f32 per gates row

#define WFRAG_OFF 0
#define A_OFF     131072
#define GATES_OFF 139520
#define BIAS_OFF  147968
#define LENS_OFF  148480
#define MAXL_OFF  148544
#define SMEM_SZ   148608

__device__ __forceinline__ u16 f2bf(float f) {
  u32 u = __float_as_uint(f);
  u32 r = u + 0x7fffu + ((u >> 16) & 1u);   // RNE bf16
  return (u16)(r >> 16);
}
__device__ __forceinline__ float sigmoidf_(float x) {
  return 1.0f / (1.0f + __expf(-x));
}
__device__ __forceinline__ float tanhf_(float x) {
  x = fminf(fmaxf(x, -40.0f), 40.0f);
  float e = __expf(-2.0f * x);
  return (1.0f - e) / (1.0f + e);
}

// Relaxed agent-scope helpers: compile to sc1 (L2-bypass) accesses serviced at
// the memory-side coherent point. NO acquire/release/threadfence anywhere in
// the hot loop -> no bulk L2 writeback/invalidate (that was the 13us/step).
// Ordering rule used: __syncthreads() drains vmcnt(0) (store acks) before the
// flag add is issued => any observer of the new counter sees the h data.
__device__ __forceinline__ u32 aload(const u32* p) {
  return __hip_atomic_load((u32*)p, __ATOMIC_RELAXED, __HIP_MEMORY_SCOPE_AGENT);
}
__device__ __forceinline__ void astore(u32* p, u32 v) {
  __hip_atomic_store(p, v, __ATOMIC_RELAXED, __HIP_MEMORY_SCOPE_AGENT);
}

__global__ __launch_bounds__(NTHR, 1)
void lstm_coop(const float* __restrict__ x, const int* __restrict__ lengths,
               const float* __restrict__ Wf, const float* __restrict__ bfp,
               const float* __restrict__ Wi, const float* __restrict__ bip,
               const float* __restrict__ Wc, const float* __restrict__ bcp,
               const float* __restrict__ Wo, const float* __restrict__ bop,
               const float* __restrict__ Wy, const float* __restrict__ byp,
               float* out, u16* hbuf, u32* cnt)
{
  extern __shared__ char smem[];
  char*  Wfrag = smem + WFRAG_OFF;          // 128KB: W slice, B-fragment order, bf16
  char*  Abuf  = smem + A_OFF;              // 16 x 264 bf16 : x_t only
  float* gates = (float*)(smem + GATES_OFF);// 16 x 132 f32
  float* biasS = (float*)(smem + BIAS_OFF); // 128 f32
  int*   lensS = (int*)(smem + LENS_OFF);   // 16
  int*   maxlS = (int*)(smem + MAXL_OFF);

  const int tid = threadIdx.x;
  const int g   = blockIdx.x & (NGRP - 1);  // group = batch block
  const int ji  = blockIdx.x >> 4;          // member 0..7 (same XCD likely; not relied on)
  const int b0  = g * BB;
  const int u0  = ji * JU;

  // ---------- one-time: weight slice -> LDS in MFMA B-fragment order ----------
  {
    const float* Wg_[4] = {Wf, Wi, Wc, Wo};
    for (int idx = tid; idx < NT_CNT * KT_CNT * 64; idx += NTHR) {
      int n  = idx >> 10;           // n-tile (16 cols)
      int kt = (idx >> 6) & 15;     // k-tile (32 k)
      int l  = idx & 63;            // lane
      int cl = n * 16 + (l & 15);   // local gate-col 0..127: [f|i|c|o] x 32 units
      const float* W = Wg_[cl >> 5];
      int col = u0 + (cl & 31);
      int k0  = kt * 32 + (l >> 4) * 8;
      uint4 v;
      u32* pv = (u32*)&v;
      #pragma unroll
      for (int m = 0; m < 4; m++) {
        float f0 = W[(size_t)(k0 + 2*m    ) * H_DIM + col];
        float f1 = W[(size_t)(k0 + 2*m + 1) * H_DIM + col];
        pv[m] = (u32)f2bf(f0) | ((u32)f2bf(f1) << 16);
      }
      *(uint4*)(Wfrag + (size_t)idx * 16) = v;
    }
    const float* bg_[4] = {bfp, bip, bcp, bop};
    if (tid < JC) biasS[tid] = bg_[tid >> 5][u0 + (tid & 31)];
    if (tid < BB) lensS[tid] = lengths[b0 + tid];
  }
  __syncthreads();
  if (tid == 0) {
    int m = 1;
    for (int r = 0; r < BB; r++) m = max(m, lensS[r]);
    maxlS[0] = m;
  }
  __syncthreads();
  const int Tmax = maxlS[0];

  // per-thread persistent state: 2 adjacent (b,u) cells
  const int pb = tid >> 4;
  const int pu = (tid * 2) & 31;
  const int lenb = lensS[pb];
  float cst0 = 0.f, cst1 = 0.f, hst0 = 0.f, hst1 = 0.f;

  const int l    = tid & 63;
  const int wv   = tid >> 6;        // wave 0..3, owns n-tiles {2wv, 2wv+1}
  const int arow = l & 15;          // A row (batch)
  const int kh   = l >> 4;          // k-half-group 0..3 (8 k each)
  const char* Aread  = Abuf + arow * APITCH_B + kh * 16;
  const char* Bbase0 = Wfrag + ((size_t)((2*wv    ) * KT_CNT) * 64 + l) * 16;
  const char* Bbase1 = Wfrag + ((size_t)((2*wv + 1) * KT_CNT) * 64 + l) * 16;
  u32* cslot = cnt + g * 32;        // 128B-spaced per-group barrier counter

  for (int t = 0; t < Tmax; t++) {
    // ---- stage x_t as bf16 into LDS (independent of h; overlaps sibling wait) ----
    const float* xrow = x + ((size_t)t * B_DIM + b0) * D_DIM;
    #pragma unroll
    for (int i = tid; i < BB * 128; i += NTHR) {
      int r = i >> 7, dp = i & 127;
      float2 xv = *(const float2*)(xrow + (size_t)r * D_DIM + dp * 2);
      *(u32*)(Abuf + r * APITCH_B + dp * 4) =
          (u32)f2bf(xv.x) | ((u32)f2bf(xv.y) << 16);
    }
    __syncthreads();                               // S1: x staged

    // ---- x-part GEMM (K 0..255) ----
    f32x4 acc0 = {0.f, 0.f, 0.f, 0.f};
    f32x4 acc1 = {0.f, 0.f, 0.f, 0.f};
    #pragma unroll
    for (int kt = 0; kt < KT_X; kt++) {
      bf16x8 a   = *(const bf16x8*)(Aread  + kt * 64);
      bf16x8 b0v = *(const bf16x8*)(Bbase0 + (size_t)kt * 1024);
      bf16x8 b1v = *(const bf16x8*)(Bbase1 + (size_t)kt * 1024);
      acc0 = __builtin_amdgcn_mfma_f32_16x16x32_bf16(a, b0v, acc0, 0, 0, 0);
      acc1 = __builtin_amdgcn_mfma_f32_16x16x32_bf16(a, b1v, acc1, 0, 0, 0);
    }

    // ---- wait for h_t (all siblings finished step t-1); relaxed poll only ----
    if (tid == 0) {
      const u32 tgt = (u32)t * NJ;
      while (aload(cslot) < tgt) __builtin_amdgcn_s_sleep(1);
    }
    __syncthreads();                               // S2: h_t globally visible

    // ---- h-part GEMM (K 256..511): per-lane direct sc1 loads into A-frags ----
    {
      const u16* hin = hbuf + (size_t)(t & 1) * (B_DIM * H_DIM);
      const u32* hbase = (const u32*)(hin + (size_t)(b0 + arow) * H_DIM) + kh * 4;
      u32 hw[8][4];
      #pragma unroll
      for (int kt2 = 0; kt2 < 8; kt2++) {
        const u32* hp = hbase + kt2 * 16;          // 32 units per kt2
        #pragma unroll
        for (int m = 0; m < 4; m++) hw[kt2][m] = aload(hp + m);
      }
      #pragma unroll
      for (int kt2 = 0; kt2 < 8; kt2++) {
        union { u32 w[4]; bf16x8 v; } au;
        au.w[0] = hw[kt2][0]; au.w[1] = hw[kt2][1];
        au.w[2] = hw[kt2][2]; au.w[3] = hw[kt2][3];
        bf16x8 b0v = *(const bf16x8*)(Bbase0 + (size_t)(kt2 + 8) * 1024);
        bf16x8 b1v = *(const bf16x8*)(Bbase1 + (size_t)(kt2 + 8) * 1024);
        acc0 = __builtin_amdgcn_mfma_f32_16x16x32_bf16(au.v, b0v, acc0, 0, 0, 0);
        acc1 = __builtin_amdgcn_mfma_f32_16x16x32_bf16(au.v, b1v, acc1, 0, 0, 0);
      }
    }

    // ---- transpose gates via LDS ----
    #pragma unroll
    for (int r = 0; r < 4; r++) {     // C layout: col=lane&15, row=(lane>>4)*4+r
      int gr = kh * 4 + r;
      gates[gr * GPITCH + (2*wv    ) * 16 + arow] = acc0[r];
      gates[gr * GPITCH + (2*wv + 1) * 16 + arow] = acc1[r];
    }
    __syncthreads();                               // S3: gates written

    // ---- gates + masked state update + publish h_{t+1} ----
    {
      const float* gp = gates + pb * GPITCH;
      const bool act = (t < lenb);
      int u = pu;
      float fg = sigmoidf_(gp[u]      + biasS[u]);
      float ig = sigmoidf_(gp[32 + u] + biasS[32 + u]);
      float cg = tanhf_  (gp[64 + u]  + biasS[64 + u]);
      float og = sigmoidf_(gp[96 + u] + biasS[96 + u]);
      if (act) { cst0 = fg * cst0 + ig * cg; hst0 = og * tanhf_(cst0); }
      u = pu + 1;
      fg = sigmoidf_(gp[u]      + biasS[u]);
      ig = sigmoidf_(gp[32 + u] + biasS[32 + u]);
      cg = tanhf_  (gp[64 + u]  + biasS[64 + u]);
      og = sigmoidf_(gp[96 + u] + biasS[96 + u]);
      if (act) { cst1 = fg * cst1 + ig * cg; hst1 = og * tanhf_(cst1); }

      u16* hout = hbuf + (size_t)((t + 1) & 1) * (B_DIM * H_DIM);
      u32 pk = (u32)f2bf(hst0) | ((u32)f2bf(hst1) << 16);
      astore((u32*)(hout + (size_t)(b0 + pb) * H_DIM + u0 + pu), pk);
    }

    // S4: drains vmcnt(0) -> h stores acked at coherent point BEFORE the add
    __syncthreads();
    if (tid == 0)
      __hip_atomic_fetch_add(cslot, 1u, __ATOMIC_RELAXED, __HIP_MEMORY_SCOPE_AGENT);
  }

  // ---- publish final f32 h, group barrier, then y = h @ Wy + by ----
  {
    float* hOut = out + (size_t)B_DIM * O_DIM;
    u32* dst = (u32*)(hOut + (size_t)(b0 + pb) * H_DIM + u0 + pu);
    astore(dst + 0, __float_as_uint(hst0));
    astore(dst + 1, __float_as_uint(hst1));
  }
  __syncthreads();                                 // drain final h stores
  if (tid == 0)
    __hip_atomic_fetch_add(cslot, 1u, __ATOMIC_RELAXED, __HIP_MEMORY_SCOPE_AGENT);

  if (ji == 0) {
    if (tid == 0) {
      const u32 tgt = (u32)Tmax * NJ + NJ;
      while (aload(cslot) < tgt) __builtin_amdgcn_s_sleep(1);
    }
    __syncthreads();
    float* hS = (float*)Abuf;                      // reuse LDS: 16x256 f32 (8KB)
    const float* hOut = out + (size_t)B_DIM * O_DIM;
    for (int i = tid; i < BB * H_DIM; i += NTHR) {
      int r = i >> 8, u = i & 255;
      hS[r * H_DIM + u] = __uint_as_float(aload((u32*)(hOut + (size_t)(b0 + r) * H_DIM + u)));
    }
    __syncthreads();
    int b = tid >> 4;
    int o = (tid & 15) * 4;
    const float* hrow = hS + b * H_DIM;
    float a0 = 0.f, a1 = 0.f, a2 = 0.f, a3 = 0.f;
    #pragma unroll 4
    for (int u = 0; u < H_DIM; u++) {
      float4 wy = *(const float4*)(Wy + (size_t)u * O_DIM + o);
      float hv = hrow[u];
      a0 = fmaf(hv, wy.x, a0);
      a1 = fmaf(hv, wy.y, a1);
      a2 = fmaf(hv, wy.z, a2);
      a3 = fmaf(hv, wy.w, a3);
    }
    float4 bv = *(const float4*)(byp + o);
    float4 yv = {a0 + bv.x, a1 + bv.y, a2 + bv.z, a3 + bv.w};
    *(float4*)(out + (size_t)(b0 + b) * O_DIM + o) = yv;
  }
}

extern "C" void kernel_launch(void* const* d_in, const int* in_sizes, int n_in,
                              void* d_out, int out_size, void* d_ws, size_t ws_size,
                              hipStream_t stream)
{
  (void)in_sizes; (void)n_in; (void)out_size; (void)ws_size;
  const float* x   = (const float*)d_in[0];
  const int*   ln  = (const int*)d_in[1];
  const float* Wf  = (const float*)d_in[2];
  const float* bf_ = (const float*)d_in[3];
  const float* Wi  = (const float*)d_in[4];
  const float* bi_ = (const float*)d_in[5];
  const float* Wc  = (const float*)d_in[6];
  const float* bc_ = (const float*)d_in[7];
  const float* Wo  = (const float*)d_in[8];
  const float* bo_ = (const float*)d_in[9];
  const float* Wy  = (const float*)d_in[10];
  const float* by_ = (const float*)d_in[11];
  float* out = (float*)d_out;

  // ws layout: [0,2048) barrier counters (128B/group) | [2048, +128K) h buf0 | +128K h buf1
  u32* cnt  = (u32*)d_ws;
  u16* hbuf = (u16*)((char*)d_ws + 2048);
  hipMemsetAsync(d_ws, 0, 2048 + (size_t)B_DIM * H_DIM * 2, stream); // zero counters + h0

  void* args[] = {&x, &ln, &Wf, &bf_, &Wi, &bi_, &Wc, &bc_, &Wo, &bo_,
                  &Wy, &by_, &out, &hbuf, &cnt};
  hipLaunchCooperativeKernel((void*)lstm_coop, dim3(NWG), dim3(NTHR),
                             args, SMEM_SZ, stream);
}

// Round 7
// 2640.082 us; speedup vs baseline: 2.5480x; 1.4220x over previous
//
#include <hip/hip_runtime.h>
#include <stdint.h>

typedef unsigned int   u32;
typedef unsigned short u16;
typedef unsigned long long u64;
typedef __attribute__((ext_vector_type(8))) short bf16x8;
typedef __attribute__((ext_vector_type(4))) float f32x4;
typedef __attribute__((ext_vector_type(4))) u32 u32x4;

#define B_DIM  256
#define D_DIM  256
#define H_DIM  256
#define O_DIM  64
#define BB     16
#define NJ     8
#define JU     32
#define JC     128
#define NGRP   16
#define NWG    128
#define NTHR   256
#define KT_CNT 16
#define KT_X   8
#define NT_CNT 8
#define APITCH_B 528
#define GPITCH 132

#define WFRAG_OFF 0
#define A_OFF     131072
#define GATES_OFF 139520
#define BIAS_OFF  147968
#define LENS_OFF  148480
#define MAXL_OFF  148544
#define XCCS_OFF  148548
#define SMEM_SZ   148608

// ws layout (u32 indices into ctl): [0,512) per-group slow counters (g*32);
// 512: startup counter; 528+g*16: fast flag line (64B/group); 784+: xcc table.
#define CSLOT_IX(g)  ((g) * 32)
#define START_IX     512
#define FLAGS_IX(g)  (528 + (g) * 16)
#define XCCT_IX      784
#define HBUF_BYTE_OFF 4096

#define SPIN_FALLBACK 1024   // fast-poll iterations before also accepting sc1 counter

__device__ __forceinline__ u16 f2bf(float f) {
  u32 u = __float_as_uint(f);
  u32 r = u + 0x7fffu + ((u >> 16) & 1u);
  return (u16)(r >> 16);
}
__device__ __forceinline__ float sigmoidf_(float x) {
  return 1.0f / (1.0f + __expf(-x));
}
__device__ __forceinline__ float tanhf_(float x) {
  x = fminf(fmaxf(x, -40.0f), 40.0f);
  float e = __expf(-2.0f * x);
  return (1.0f - e) / (1.0f + e);
}
// sc1 (MALL, cross-XCD-safe) relaxed ops — the verified round-3 path.
__device__ __forceinline__ u32 aload(const u32* p) {
  return __hip_atomic_load((u32*)p, __ATOMIC_RELAXED, __HIP_MEMORY_SCOPE_AGENT);
}
__device__ __forceinline__ void astore(u32* p, u32 v) {
  __hip_atomic_store(p, v, __ATOMIC_RELAXED, __HIP_MEMORY_SCOPE_AGENT);
}
// sc0 (bypass L1, hit local XCD L2) — only valid when all parties share an XCD.
__device__ __forceinline__ void st_sc0(u64 addr, u32 v) {
  asm volatile("global_store_dword %0, %1, off sc0" :: "v"(addr), "v"(v) : "memory");
}
__device__ __forceinline__ void vm_drain() {
  asm volatile("s_waitcnt vmcnt(0)" ::: "memory");
}

__global__ __launch_bounds__(NTHR, 1)
void lstm_coop(const float* __restrict__ x, const int* __restrict__ lengths,
               const float* __restrict__ Wf, const float* __restrict__ bfp,
               const float* __restrict__ Wi, const float* __restrict__ bip,
               const float* __restrict__ Wc, const float* __restrict__ bcp,
               const float* __restrict__ Wo, const float* __restrict__ bop,
               const float* __restrict__ Wy, const float* __restrict__ byp,
               float* out, u16* hbuf, u32* ctl)
{
  extern __shared__ char smem[];
  char*  Wfrag = smem + WFRAG_OFF;
  char*  Abuf  = smem + A_OFF;
  float* gates = (float*)(smem + GATES_OFF);
  float* biasS = (float*)(smem + BIAS_OFF);
  int*   lensS = (int*)(smem + LENS_OFF);
  int*   maxlS = (int*)(smem + MAXL_OFF);
  int*   xccS  = (int*)(smem + XCCS_OFF);   // 8 entries

  const int tid = threadIdx.x;
  const int g   = blockIdx.x & (NGRP - 1);
  const int ji  = blockIdx.x >> 4;
  const int b0  = g * BB;
  const int u0  = ji * JU;

  u32* cslot  = ctl + CSLOT_IX(g);
  u32* startp = ctl + START_IX;
  u32* flags  = ctl + FLAGS_IX(g);
  u32* xcct   = ctl + XCCT_IX;

  u32 xcc;
  asm volatile("s_getreg_b32 %0, hwreg(HW_REG_XCC_ID)" : "=s"(xcc));

  // ---------- startup: zero-init fast-path state via OWN L2, publish XCC ----------
  {
    // zero this member's h-slice of buf0 through local L2 (sc0) — never trust
    // memset residency for L2-path reads.
    u32* h0 = (u32*)((char*)hbuf);          // buf0 base as u32
    int row = tid >> 4, w = tid & 15;       // 256 threads = 16 rows x 16 u32
    u64 za = (u64)(uintptr_t)(h0 + (size_t)(b0 + row) * 128 + (u0 >> 1) + w);
    st_sc0(za, 0u);
    if (ji == 0 && tid < 8)                 // zero the group's flag line
      st_sc0((u64)(uintptr_t)(flags + tid), 0u);
    vm_drain();
  }
  __syncthreads();
  if (tid == 0) {
    astore(xcct + blockIdx.x, xcc);         // publish placement (sc1)
    vm_drain();
    __hip_atomic_fetch_add(startp, 1u, __ATOMIC_RELAXED, __HIP_MEMORY_SCOPE_AGENT);
  }

  // ---------- one-time: weight slice -> LDS in MFMA B-fragment order ----------
  {
    const float* Wg_[4] = {Wf, Wi, Wc, Wo};
    for (int idx = tid; idx < NT_CNT * KT_CNT * 64; idx += NTHR) {
      int n  = idx >> 10;
      int kt = (idx >> 6) & 15;
      int l  = idx & 63;
      int cl = n * 16 + (l & 15);
      const float* W = Wg_[cl >> 5];
      int col = u0 + (cl & 31);
      int k0  = kt * 32 + (l >> 4) * 8;
      uint4 v;
      u32* pv = (u32*)&v;
      #pragma unroll
      for (int m = 0; m < 4; m++) {
        float f0 = W[(size_t)(k0 + 2*m    ) * H_DIM + col];
        float f1 = W[(size_t)(k0 + 2*m + 1) * H_DIM + col];
        pv[m] = (u32)f2bf(f0) | ((u32)f2bf(f1) << 16);
      }
      *(uint4*)(Wfrag + (size_t)idx * 16) = v;
    }
    const float* bg_[4] = {bfp, bip, bcp, bop};
    if (tid < JC) biasS[tid] = bg_[tid >> 5][u0 + (tid & 31)];
    if (tid < BB) lensS[tid] = lengths[b0 + tid];
  }
  __syncthreads();
  if (tid == 0) {
    int m = 1;
    for (int r = 0; r < BB; r++) m = max(m, lensS[r]);
    maxlS[0] = m;
    // global startup barrier: all 128 wgs arrived (orders xcc table + all inits)
    while (aload(startp) < (u32)NWG) __builtin_amdgcn_s_sleep(1);
  }
  __syncthreads();
  if (tid < 8) xccS[tid] = (int)aload(xcct + g + 16 * tid);
  __syncthreads();
  const int Tmax = maxlS[0];
  bool fast = true;
  #pragma unroll
  for (int j = 1; j < 8; j++) fast = fast && (xccS[j] == xccS[0]);

  const int pb = tid >> 4;
  const int pu = (tid * 2) & 31;
  const int lenb = lensS[pb];
  float cst0 = 0.f, cst1 = 0.f, hst0 = 0.f, hst1 = 0.f;

  const int l    = tid & 63;
  const int wv   = tid >> 6;
  const int arow = l & 15;
  const int kh   = l >> 4;
  const char* Aread  = Abuf + arow * APITCH_B + kh * 16;
  const char* Bbase0 = Wfrag + ((size_t)((2*wv    ) * KT_CNT) * 64 + l) * 16;
  const char* Bbase1 = Wfrag + ((size_t)((2*wv + 1) * KT_CNT) * 64 + l) * 16;
  const u64 flg_addr = (u64)(uintptr_t)(flags + ji);

#define HKT(HV, KT2) do {                                                     \
    bf16x8 a_ = __builtin_bit_cast(bf16x8, HV);                               \
    bf16x8 b0_ = *(const bf16x8*)(Bbase0 + (size_t)((KT2) + 8) * 1024);       \
    bf16x8 b1_ = *(const bf16x8*)(Bbase1 + (size_t)((KT2) + 8) * 1024);       \
    acc0 = __builtin_amdgcn_mfma_f32_16x16x32_bf16(a_, b0_, acc0, 0, 0, 0);   \
    acc1 = __builtin_amdgcn_mfma_f32_16x16x32_bf16(a_, b1_, acc1, 0, 0, 0);   \
  } while (0)

// Fast group-wait: poll sc0 flag line; after SPIN_FALLBACK iters also accept
// the sc1 mirror counter (hang-proofing if sc0 visibility assumption fails).
#define FAST_WAIT(TG, CTGT) do {                                              \
    const u32 tg_ = (TG);                                                     \
    const u64 fa_ = (u64)(uintptr_t)flags;                                    \
    int spins_ = 0;                                                           \
    for (;;) {                                                                \
      u32x4 fa0, fa1;                                                         \
      asm volatile(                                                           \
        "global_load_dwordx4 %0, %2, off sc0\n\t"                             \
        "global_load_dwordx4 %1, %2, off offset:16 sc0\n\t"                   \
        "s_waitcnt vmcnt(0)"                                                  \
        : "=v"(fa0), "=v"(fa1) : "v"(fa_) : "memory");                        \
      if (fa0[0] >= tg_ && fa0[1] >= tg_ && fa0[2] >= tg_ && fa0[3] >= tg_ && \
          fa1[0] >= tg_ && fa1[1] >= tg_ && fa1[2] >= tg_ && fa1[3] >= tg_)   \
        break;                                                                \
      if (++spins_ > SPIN_FALLBACK && aload(cslot) >= (CTGT)) break;          \
      __builtin_amdgcn_s_sleep(1);                                            \
    }                                                                         \
  } while (0)

  for (int t = 0; t < Tmax; t++) {
    // ---- stage x_t (independent of h; overlaps sibling wait) ----
    const float* xrow = x + ((size_t)t * B_DIM + b0) * D_DIM;
    #pragma unroll
    for (int i = tid; i < BB * 128; i += NTHR) {
      int r = i >> 7, dp = i & 127;
      float2 xv = *(const float2*)(xrow + (size_t)r * D_DIM + dp * 2);
      *(u32*)(Abuf + r * APITCH_B + dp * 4) =
          (u32)f2bf(xv.x) | ((u32)f2bf(xv.y) << 16);
    }
    __syncthreads();

    // ---- x-part GEMM (K 0..255) ----
    f32x4 acc0 = {0.f, 0.f, 0.f, 0.f};
    f32x4 acc1 = {0.f, 0.f, 0.f, 0.f};
    #pragma unroll
    for (int kt = 0; kt < KT_X; kt++) {
      bf16x8 a   = *(const bf16x8*)(Aread  + kt * 64);
      bf16x8 b0v = *(const bf16x8*)(Bbase0 + (size_t)kt * 1024);
      bf16x8 b1v = *(const bf16x8*)(Bbase1 + (size_t)kt * 1024);
      acc0 = __builtin_amdgcn_mfma_f32_16x16x32_bf16(a, b0v, acc0, 0, 0, 0);
      acc1 = __builtin_amdgcn_mfma_f32_16x16x32_bf16(a, b1v, acc1, 0, 0, 0);
    }

    // ---- wait: all siblings finished step t-1 ----
    if (tid == 0) {
      if (fast) {
        FAST_WAIT((u32)t, (u32)t * NJ);
      } else {
        const u32 tgt = (u32)t * NJ;
        while (aload(cslot) < tgt) __builtin_amdgcn_s_sleep(1);
      }
    }
    __syncthreads();

    // ---- h-part GEMM (K 256..511): direct loads into A-fragments ----
    {
      const u16* hin = hbuf + (size_t)(t & 1) * (B_DIM * H_DIM);
      const u32* hbase = (const u32*)(hin + (size_t)(b0 + arow) * H_DIM) + kh * 4;
      u32x4 hv0, hv1, hv2, hv3, hv4, hv5, hv6, hv7;
      if (fast) {
        const u64 ha = (u64)(uintptr_t)hbase;
        asm volatile(
          "global_load_dwordx4 %0, %8, off sc0\n\t"
          "global_load_dwordx4 %1, %8, off offset:64 sc0\n\t"
          "global_load_dwordx4 %2, %8, off offset:128 sc0\n\t"
          "global_load_dwordx4 %3, %8, off offset:192 sc0\n\t"
          "global_load_dwordx4 %4, %8, off offset:256 sc0\n\t"
          "global_load_dwordx4 %5, %8, off offset:320 sc0\n\t"
          "global_load_dwordx4 %6, %8, off offset:384 sc0\n\t"
          "global_load_dwordx4 %7, %8, off offset:448 sc0\n\t"
          "s_waitcnt vmcnt(0)"
          : "=v"(hv0), "=v"(hv1), "=v"(hv2), "=v"(hv3),
            "=v"(hv4), "=v"(hv5), "=v"(hv6), "=v"(hv7)
          : "v"(ha) : "memory");
      } else {
        #define SLD(HV, KT2) { HV[0]=aload(hbase+(KT2)*16+0); HV[1]=aload(hbase+(KT2)*16+1); \
                               HV[2]=aload(hbase+(KT2)*16+2); HV[3]=aload(hbase+(KT2)*16+3); }
        SLD(hv0,0) SLD(hv1,1) SLD(hv2,2) SLD(hv3,3)
        SLD(hv4,4) SLD(hv5,5) SLD(hv6,6) SLD(hv7,7)
        #undef SLD
      }
      HKT(hv0,0); HKT(hv1,1); HKT(hv2,2); HKT(hv3,3);
      HKT(hv4,4); HKT(hv5,5); HKT(hv6,6); HKT(hv7,7);
    }

    // ---- transpose gates via LDS ----
    #pragma unroll
    for (int r = 0; r < 4; r++) {
      int gr = kh * 4 + r;
      gates[gr * GPITCH + (2*wv    ) * 16 + arow] = acc0[r];
      gates[gr * GPITCH + (2*wv + 1) * 16 + arow] = acc1[r];
    }
    __syncthreads();

    // ---- gates + masked state update + publish h_{t+1} ----
    {
      const float* gp = gates + pb * GPITCH;
      const bool act = (t < lenb);
      int u = pu;
      float fg = sigmoidf_(gp[u]      + biasS[u]);
      float ig = sigmoidf_(gp[32 + u] + biasS[32 + u]);
      float cg = tanhf_  (gp[64 + u]  + biasS[64 + u]);
      float og = sigmoidf_(gp[96 + u] + biasS[96 + u]);
      if (act) { cst0 = fg * cst0 + ig * cg; hst0 = og * tanhf_(cst0); }
      u = pu + 1;
      fg = sigmoidf_(gp[u]      + biasS[u]);
      ig = sigmoidf_(gp[32 + u] + biasS[32 + u]);
      cg = tanhf_  (gp[64 + u]  + biasS[64 + u]);
      og = sigmoidf_(gp[96 + u] + biasS[96 + u]);
      if (act) { cst1 = fg * cst1 + ig * cg; hst1 = og * tanhf_(cst1); }

      u16* hout = hbuf + (size_t)((t + 1) & 1) * (B_DIM * H_DIM);
      u32 pk = (u32)f2bf(hst0) | ((u32)f2bf(hst1) << 16);
      u32* hp = (u32*)(hout + (size_t)(b0 + pb) * H_DIM + u0 + pu);
      if (fast) st_sc0((u64)(uintptr_t)hp, pk);
      else      astore(hp, pk);
    }

    // ---- order h stores before flag, then signal ----
    vm_drain();
    __syncthreads();
    if (tid == 0) {
      if (fast) {
        st_sc0(flg_addr, (u32)(t + 1));
        // mirror to sc1 counter (fire-and-forget; fallback + diagnostics)
        __hip_atomic_fetch_add(cslot, 1u, __ATOMIC_RELAXED, __HIP_MEMORY_SCOPE_AGENT);
      } else {
        __hip_atomic_fetch_add(cslot, 1u, __ATOMIC_RELAXED, __HIP_MEMORY_SCOPE_AGENT);
      }
    }
  }

  // ---- publish final f32 h, group barrier, then y = h @ Wy + by ----
  {
    float* hOut = out + (size_t)B_DIM * O_DIM;
    u32* dst = (u32*)(hOut + (size_t)(b0 + pb) * H_DIM + u0 + pu);
    if (fast) {
      st_sc0((u64)(uintptr_t)(dst + 0), __float_as_uint(hst0));
      st_sc0((u64)(uintptr_t)(dst + 1), __float_as_uint(hst1));
    } else {
      astore(dst + 0, __float_as_uint(hst0));
      astore(dst + 1, __float_as_uint(hst1));
    }
  }
  vm_drain();
  __syncthreads();
  if (tid == 0) {
    if (fast) {
      st_sc0(flg_addr, (u32)(Tmax + 1));
      __hip_atomic_fetch_add(cslot, 1u, __ATOMIC_RELAXED, __HIP_MEMORY_SCOPE_AGENT);
    } else {
      __hip_atomic_fetch_add(cslot, 1u, __ATOMIC_RELAXED, __HIP_MEMORY_SCOPE_AGENT);
    }
  }

  if (ji == 0) {
    if (tid == 0) {
      if (fast) {
        FAST_WAIT((u32)(Tmax + 1), (u32)Tmax * NJ + NJ);
      } else {
        const u32 tgt = (u32)Tmax * NJ + NJ;
        while (aload(cslot) < tgt) __builtin_amdgcn_s_sleep(1);
      }
    }
    __syncthreads();
    float* hS = (float*)Abuf;                       // 16x256 f32
    const float* hOut = out + (size_t)B_DIM * O_DIM;
    const u32* hbase32 = (const u32*)(hOut + (size_t)b0 * H_DIM); // 4096 u32 contiguous
    if (fast) {
      #pragma unroll
      for (int c = 0; c < 4; c++) {
        int off = c * 1024 + tid * 4;
        u32x4 v;
        u64 pa = (u64)(uintptr_t)(hbase32 + off);
        asm volatile("global_load_dwordx4 %0, %1, off sc0\n\ts_waitcnt vmcnt(0)"
                     : "=v"(v) : "v"(pa) : "memory");
        *(u32x4*)((u32*)hS + off) = v;
      }
    } else {
      for (int i = tid; i < BB * H_DIM; i += NTHR) {
        ((u32*)hS)[i] = aload(hbase32 + i);
      }
    }
    __syncthreads();
    int b = tid >> 4;
    int o = (tid & 15) * 4;
    const float* hrow = hS + b * H_DIM;
    float a0 = 0.f, a1 = 0.f, a2 = 0.f, a3 = 0.f;
    #pragma unroll 4
    for (int u = 0; u < H_DIM; u++) {
      float4 wy = *(const float4*)(Wy + (size_t)u * O_DIM + o);
      float hv = hrow[u];
      a0 = fmaf(hv, wy.x, a0);
      a1 = fmaf(hv, wy.y, a1);
      a2 = fmaf(hv, wy.z, a2);
      a3 = fmaf(hv, wy.w, a3);
    }
    float4 bv = *(const float4*)(byp + o);
    float4 yv = {a0 + bv.x, a1 + bv.y, a2 + bv.z, a3 + bv.w};
    *(float4*)(out + (size_t)(b0 + b) * O_DIM + o) = yv;
  }
}

extern "C" void kernel_launch(void* const* d_in, const int* in_sizes, int n_in,
                              void* d_out, int out_size, void* d_ws, size_t ws_size,
                              hipStream_t stream)
{
  (void)in_sizes; (void)n_in; (void)out_size; (void)ws_size;
  const float* x   = (const float*)d_in[0];
  const int*   ln  = (const int*)d_in[1];
  const float* Wf  = (const float*)d_in[2];
  const float* bf_ = (const float*)d_in[3];
  const float* Wi  = (const float*)d_in[4];
  const float* bi_ = (const float*)d_in[5];
  const float* Wc  = (const float*)d_in[6];
  const float* bc_ = (const float*)d_in[7];
  const float* Wo  = (const float*)d_in[8];
  const float* bo_ = (const float*)d_in[9];
  const float* Wy  = (const float*)d_in[10];
  const float* by_ = (const float*)d_in[11];
  float* out = (float*)d_out;

  u32* ctl  = (u32*)d_ws;
  u16* hbuf = (u16*)((char*)d_ws + HBUF_BYTE_OFF);
  // zero control region + h buf0 (slow-path init; fast path re-inits via its L2)
  hipMemsetAsync(d_ws, 0, HBUF_BYTE_OFF + (size_t)B_DIM * H_DIM * 2, stream);

  void* args[] = {&x, &ln, &Wf, &bf_, &Wi, &bi_, &Wc, &bc_, &Wo, &bo_,
                  &Wy, &by_, &out, &hbuf, &ctl};
  hipLaunchCooperativeKernel((void*)lstm_coop, dim3(NWG), dim3(NTHR),
                             args, SMEM_SZ, stream);
}